// Round 4
// baseline (178.214 us; speedup 1.0000x reference)
//
#include <hip/hip_runtime.h>
#include <stdint.h>

#define N_ANCH 102400
#define FMP 320
#define K_TOP 1000
#define NMS_T 0.6f
#define SC_CLAMP 6.907755278982137f
#define IMGF 1280.0f
#define NBINS 16384   // scores in (0,1) => float bits>>16 < 0x4000

// ---- workspace layout (bytes) ----
#define OFF_SCORES   0u          // f32[102400]
#define OFF_LABELS   409600u     // u32[102400]
#define OFF_BOXES    917760u     // f32[4000]
#define OFF_LAB1K    933760u     // u32[1000]
#define OFF_MASK     937760u     // u64[16000]
#define OFF_DIAG     1065760u    // u64[1024]

__device__ __forceinline__ float sigf(float x) {
    return 1.0f / (1.0f + expf(-x));
}

// ---------------- K1: scores+argmax; fused zeroing of diag tail ----------------
__global__ __launch_bounds__(256) void k_scores(const float* __restrict__ hmp,
                                                const float* __restrict__ iou,
                                                float* __restrict__ scores,
                                                uint32_t* __restrict__ labels,
                                                uint64_t* __restrict__ diag) {
    int blk = blockIdx.x;
    if (blk == 0) {
        // zero diag (k_mask only rewrites rows < 1000; k_scan reads all 1024;
        // harness re-poisons ws every iteration so this is mandatory)
#pragma unroll
        for (int k = 0; k < 4; ++k) diag[threadIdx.x * 4 + k] = 0ull;
    }
    int gid = blk * 256 + threadIdx.x;
    int a = gid >> 2;
    int q = gid & 3;
    float si = sigf(iou[a]);
    const float4* row4 = (const float4*)hmp + (size_t)a * 20 + q;
    float4 v[5];
#pragma unroll
    for (int j = 0; j < 5; ++j) v[j] = row4[j * 4];
    float best = -1.0f;
    int bc = 0;
#pragma unroll
    for (int j = 0; j < 5; ++j) {
        int cb = j * 16 + q * 4;
        float f;
        f = sqrtf(sigf(v[j].x) * si); if (f > best) { best = f; bc = cb; }
        f = sqrtf(sigf(v[j].y) * si); if (f > best) { best = f; bc = cb + 1; }
        f = sqrtf(sigf(v[j].z) * si); if (f > best) { best = f; bc = cb + 2; }
        f = sqrtf(sigf(v[j].w) * si); if (f > best) { best = f; bc = cb + 3; }
    }
#pragma unroll
    for (int off = 1; off <= 2; off <<= 1) {
        float of = __shfl_xor(best, off);
        int   oc = __shfl_xor(bc, off);
        if (of > best || (of == best && oc < bc)) { best = of; bc = oc; }
    }
    if (q == 0) {
        scores[a] = best;
        labels[a] = (uint32_t)bc;
    }
}

// ---------------- K2: single-block hist -> cutoff -> collect -> bucket-rank -> decode ----------------
// rank(c) = suffix(bin_c + 1) + #{same-bin keys > key_c}. The fine histogram gives
// suffix counts; buckets (avg ~6 elems) replace the old O(M^2) pairwise rank, so the
// whole top-k pipeline fits one block with zero cross-block sync and no global keys.
__global__ __launch_bounds__(1024) void k_topk(const float* __restrict__ scores,
                                               const uint32_t* __restrict__ labels,
                                               const float* __restrict__ reg,
                                               float* __restrict__ out,
                                               float* __restrict__ boxes,
                                               uint32_t* __restrict__ lab1k) {
    __shared__ uint32_t lh[NBINS];        // 64 KB fine histogram (original counts kept)
    __shared__ uint32_t coarse[1025];     // suffix sums at 16-bin granularity
    __shared__ uint64_t skey[4096];       // candidate keys, bucketed by bin
    __shared__ uint32_t cnt[2048];        // per-bin arrival counters, indexed bin-cut
    __shared__ uint16_t sst[4096];        // bucket start per slot
    __shared__ uint16_t sen[4096];        // bucket end per slot
    __shared__ uint32_t s_cut, s_m;

    const int tid = threadIdx.x;
    for (int i = tid; i < NBINS; i += 1024) lh[i] = 0u;
    for (int i = tid; i < 2048; i += 1024) cnt[i] = 0u;
    if (tid == 0) { s_cut = 0u; coarse[1024] = 0u; }
    __syncthreads();

    // --- fine histogram: 25600 float4 / 1024 threads ---
    const float4* s4 = (const float4*)scores;
    for (int k = tid; k < N_ANCH / 4; k += 1024) {
        float4 v = s4[k];
        atomicAdd(&lh[__float_as_uint(v.x) >> 16], 1u);
        atomicAdd(&lh[__float_as_uint(v.y) >> 16], 1u);
        atomicAdd(&lh[__float_as_uint(v.z) >> 16], 1u);
        atomicAdd(&lh[__float_as_uint(v.w) >> 16], 1u);
    }
    __syncthreads();

    // --- coarse sums (16 bins/thread) + suffix scan; lh keeps original counts ---
    {
        uint32_t s = 0;
#pragma unroll
        for (int b = 0; b < 16; ++b) s += lh[tid * 16 + b];
        coarse[tid] = s;
    }
    __syncthreads();
    for (int off = 1; off < 1024; off <<= 1) {
        uint32_t v = coarse[tid] + ((tid + off < 1024) ? coarse[tid + off] : 0u);
        __syncthreads();
        coarse[tid] = v;
        __syncthreads();
    }
    {
        uint32_t inc   = coarse[tid];
        uint32_t above = (tid < 1023) ? coarse[tid + 1] : 0u;
        if (above < K_TOP && inc >= K_TOP) {
            uint32_t c2 = above;
            for (int b = 15; b >= 0; --b) {
                c2 += lh[tid * 16 + b];
                if (c2 >= K_TOP) { s_cut = (uint32_t)(tid * 16 + b); break; }
            }
        }
    }
    __syncthreads();
    const uint32_t cut = s_cut;
    if (tid == 0) {
        // M = suffix(cut)  (reads coarse/lh only; racers below also only read them)
        uint32_t tc = cut >> 4;
        uint32_t m = coarse[tc + 1];
        for (uint32_t k2 = cut; k2 < tc * 16 + 16; ++k2) m += lh[k2];
        s_m = (m > 4096u) ? 4096u : m;
    }

    // --- collect: bucketed append.  bucket(b) occupies [suffix(b+1), suffix(b)) ---
    for (int k = tid; k < N_ANCH / 4; k += 1024) {
        float4 v = s4[k];
        uint32_t bb[4] = { __float_as_uint(v.x), __float_as_uint(v.y),
                           __float_as_uint(v.z), __float_as_uint(v.w) };
#pragma unroll
        for (int c = 0; c < 4; ++c) {
            uint32_t b = bb[c] >> 16;
            if (b >= cut) {
                uint32_t tb = b >> 4;
                uint32_t base = coarse[tb + 1];
                for (uint32_t k2 = b + 1; k2 < tb * 16 + 16; ++k2) base += lh[k2];
                uint32_t sp = b - cut;
                if (sp < 2048u) {   // span guard (cut < 14208 impossible for sane data; keeps memory-safety)
                    uint32_t slot = atomicAdd(&cnt[sp], 1u);
                    uint32_t pos  = base + slot;
                    uint32_t end  = base + lh[b];
                    if (pos < 4096u) {
                        skey[pos] = ((uint64_t)bb[c] << 32) |
                                    (uint64_t)(0xFFFFFFFFu - (uint32_t)(k * 4 + c));
                        sst[pos] = (uint16_t)base;
                        sen[pos] = (uint16_t)((end > 4096u) ? 4096u : end);
                    }
                }
            }
        }
    }
    __syncthreads();

    // --- bucket-rank + decode epilogue ---
    const uint32_t M = s_m;
    for (uint32_t s2 = tid; s2 < M; s2 += 1024) {
        uint64_t key = skey[s2];
        uint32_t st = sst[s2], en = sen[s2];
        uint32_t r = st;
        for (uint32_t u = st; u < en; ++u) r += (skey[u] > key) ? 1u : 0u;
        if (r >= K_TOP) continue;
        int t = (int)r;
        uint32_t sbits = (uint32_t)(key >> 32);
        uint32_t idx   = 0xFFFFFFFFu - (uint32_t)(key & 0xFFFFFFFFull);
        float score = __uint_as_float(sbits);
        uint32_t lab = labels[idx];
        out[t]         = score;
        out[K_TOP + t] = (float)lab;
        lab1k[t]       = lab;
        float ax = (float)(idx % FMP);
        float ay = (float)(idx / FMP);
        float4 rr = ((const float4*)reg)[idx];
        float e0 = expf(fminf(rr.x, SC_CLAMP));
        float e1 = expf(fminf(rr.y, SC_CLAMP));
        float e2 = expf(fminf(rr.z, SC_CLAMP));
        float e3 = expf(fminf(rr.w, SC_CLAMP));
        float x1 = fminf(fmaxf((ax - e0) * 4.0f / IMGF, 0.0f), 1.0f);
        float y1 = fminf(fmaxf((ay - e1) * 4.0f / IMGF, 0.0f), 1.0f);
        float x2 = fminf(fmaxf((ax + e2) * 4.0f / IMGF, 0.0f), 1.0f);
        float y2 = fminf(fmaxf((ay + e3) * 4.0f / IMGF, 0.0f), 1.0f);
        out[2 * K_TOP + t * 4 + 0] = x1;
        out[2 * K_TOP + t * 4 + 1] = y1;
        out[2 * K_TOP + t * 4 + 2] = x2;
        out[2 * K_TOP + t * 4 + 3] = y2;
        boxes[t * 4 + 0] = x1;
        boxes[t * 4 + 1] = y1;
        boxes[t * 4 + 2] = x2;
        boxes[t * 4 + 3] = y2;
    }
}

// ---------------- K3: suppress masks, one wave per row (63 x 1024) ----------------
__global__ __launch_bounds__(1024) void k_mask(const float* __restrict__ boxes,
                                               const uint32_t* __restrict__ lab1k,
                                               uint64_t* __restrict__ mask,
                                               uint64_t* __restrict__ diag) {
    int r = blockIdx.x * 16 + (threadIdx.x >> 6);
    int lane = threadIdx.x & 63;
    if (r >= K_TOP) return;
    float4 bi = ((const float4*)boxes)[r];
    uint32_t li = lab1k[r];
    float areai = (bi.z - bi.x) * (bi.w - bi.y);
    int iw = r >> 6;
    uint64_t dw = 0ull;
#pragma unroll
    for (int w = 0; w < 16; ++w) {
        int j = w * 64 + lane;
        bool sup = false;
        if (j < K_TOP && j > r) {
            float4 bj = ((const float4*)boxes)[j];
            float areaj = (bj.z - bj.x) * (bj.w - bj.y);
            float xx1 = fmaxf(bi.x, bj.x);
            float yy1 = fmaxf(bi.y, bj.y);
            float xx2 = fminf(bi.z, bj.z);
            float yy2 = fminf(bi.w, bj.w);
            float ww = fmaxf(1e-10f, xx2 - xx1);
            float hh = fmaxf(1e-10f, yy2 - yy1);
            float inter = ww * hh;
            float iouv = inter / (areai + areaj - inter + 1e-10f);
            sup = (iouv > NMS_T) && (li == lab1k[j]);
        }
        unsigned long long m = __ballot(sup);
        if (lane == 0) mask[(size_t)r * 16 + w] = (uint64_t)m;
        if (w == iw) dw = (uint64_t)m;
    }
    if (lane == 0) diag[r] = dw;
}

// ---------------- K4: greedy scan, single wave, full register budget ----------------
// launch_bounds(64,1): VGPR cap ~512 so bun[16] (32 VGPRs) can't spill
// (earlier fused versions compiled at VGPR=40 -> scratch -> 70-100us).
__global__ __launch_bounds__(64, 1) void k_scan(const uint64_t* __restrict__ mask,
                                                const uint64_t* __restrict__ diag,
                                                float* __restrict__ out) {
    int lane = threadIdx.x;
    int q = lane >> 4, wrd = lane & 15;
    uint64_t remv = 0ull;
    uint64_t dcur = diag[lane];
    for (int g = 0; g < 16; ++g) {
        uint64_t dnxt = (g < 15) ? diag[64 * (g + 1) + lane] : 0ull;
        uint64_t bun[16];
        if (g < 15) {
#pragma unroll
            for (int r4 = 0; r4 < 16; ++r4)
                bun[r4] = mask[(size_t)(64 * g + 4 * r4 + q) * 16 + wrd];
        }
        uint32_t dlo = 0, dhi = 0;
#pragma unroll
        for (int qq = 0; qq < 4; ++qq) {
            dlo |= __builtin_amdgcn_readlane((uint32_t)remv, qq * 16 + g);
            dhi |= __builtin_amdgcn_readlane((uint32_t)(remv >> 32), qq * 16 + g);
        }
        uint64_t D = ((uint64_t)dhi << 32) | dlo;
#pragma unroll
        for (int b = 0; b < 64; ++b) {
            uint32_t tlo = __builtin_amdgcn_readlane((uint32_t)dcur, b);
            uint32_t thi = __builtin_amdgcn_readlane((uint32_t)(dcur >> 32), b);
            uint64_t T = ((uint64_t)thi << 32) | tlo;
            uint64_t sel = ((D >> b) & 1ull) - 1ull;   // ~0 if row kept
            D |= T & sel;
        }
        uint64_t keepg = ~D;
        int j = g * 64 + lane;
        if (j < K_TOP) out[6 * K_TOP + j] = (float)((keepg >> lane) & 1ull);
        if (g < 15) {
#pragma unroll
            for (int r4 = 0; r4 < 16; ++r4) {
                uint32_t kb = (uint32_t)(keepg >> (4 * r4 + q)) & 1u;
                uint64_t mm = 0ull - (uint64_t)kb;
                remv |= bun[r4] & mm;
            }
        }
        dcur = dnxt;
    }
}

extern "C" void kernel_launch(void* const* d_in, const int* in_sizes, int n_in,
                              void* d_out, int out_size, void* d_ws, size_t ws_size,
                              hipStream_t stream) {
    const float* hmp = (const float*)d_in[0];
    const float* reg = (const float*)d_in[1];
    const float* iou = (const float*)d_in[2];
    float* out = (float*)d_out;
    char* ws = (char*)d_ws;

    float*    scores = (float*)(ws + OFF_SCORES);
    uint32_t* labels = (uint32_t*)(ws + OFF_LABELS);
    float*    boxes  = (float*)(ws + OFF_BOXES);
    uint32_t* lab1k  = (uint32_t*)(ws + OFF_LAB1K);
    uint64_t* mask   = (uint64_t*)(ws + OFF_MASK);
    uint64_t* diag   = (uint64_t*)(ws + OFF_DIAG);

    k_scores<<<dim3(N_ANCH * 4 / 256), dim3(256), 0, stream>>>(hmp, iou, scores, labels, diag);
    k_topk<<<dim3(1), dim3(1024), 0, stream>>>(scores, labels, reg, out, boxes, lab1k);
    k_mask<<<dim3(63), dim3(1024), 0, stream>>>(boxes, lab1k, mask, diag);
    k_scan<<<dim3(1), dim3(64), 0, stream>>>(mask, diag, out);
}

// Round 5
// 177.671 us; speedup vs baseline: 1.0031x; 1.0031x over previous
//
#include <hip/hip_runtime.h>
#include <stdint.h>

#define N_ANCH 102400
#define FMP 320
#define K_TOP 1000
#define NMS_T 0.6f
#define SC_CLAMP 6.907755278982137f
#define IMGF 1280.0f
#define NBINS 16384   // scores in (0,1) => float bits>>16 < 0x4000

// ---- workspace layout (bytes) ----
#define OFF_SCORES   0u          // f32[102400]
#define OFF_LABELS   409600u     // u32[102400]
#define OFF_HIST     819200u     // u32[16384]
#define OFF_BOXES    917760u     // f32[4000]
#define OFF_LAB1K    933760u     // u32[1000]
#define OFF_MASK     937760u     // u64[16000]
#define OFF_DIAG     1065760u    // u64[1024]

__device__ __forceinline__ float sigf(float x) {
    return 1.0f / (1.0f + expf(-x));
}

// ---------------- K1: scores+argmax; fused zeroing of hist + diag ----------------
__global__ __launch_bounds__(256) void k_scores(const float* __restrict__ hmp,
                                                const float* __restrict__ iou,
                                                float* __restrict__ scores,
                                                uint32_t* __restrict__ labels,
                                                uint32_t* __restrict__ hist,
                                                uint64_t* __restrict__ diag) {
    int blk = blockIdx.x;
    if (blk < 64) {
        hist[blk * 256 + threadIdx.x] = 0u;     // 64*256 = 16384 bins zeroed
    } else if (blk == 64) {
        // zero diag (k_mask only rewrites rows < 1000; k_scan reads all 1024;
        // harness re-poisons ws every iteration so this is mandatory)
#pragma unroll
        for (int k = 0; k < 4; ++k) diag[threadIdx.x * 4 + k] = 0ull;
    }
    int gid = blk * 256 + threadIdx.x;
    int a = gid >> 2;
    int q = gid & 3;
    float si = sigf(iou[a]);
    const float4* row4 = (const float4*)hmp + (size_t)a * 20 + q;
    float4 v[5];
#pragma unroll
    for (int j = 0; j < 5; ++j) v[j] = row4[j * 4];
    float best = -1.0f;
    int bc = 0;
#pragma unroll
    for (int j = 0; j < 5; ++j) {
        int cb = j * 16 + q * 4;
        float f;
        f = sqrtf(sigf(v[j].x) * si); if (f > best) { best = f; bc = cb; }
        f = sqrtf(sigf(v[j].y) * si); if (f > best) { best = f; bc = cb + 1; }
        f = sqrtf(sigf(v[j].z) * si); if (f > best) { best = f; bc = cb + 2; }
        f = sqrtf(sigf(v[j].w) * si); if (f > best) { best = f; bc = cb + 3; }
    }
#pragma unroll
    for (int off = 1; off <= 2; off <<= 1) {
        float of = __shfl_xor(best, off);
        int   oc = __shfl_xor(bc, off);
        if (of > best || (of == best && oc < bc)) { best = of; bc = oc; }
    }
    if (q == 0) {
        scores[a] = best;
        labels[a] = (uint32_t)bc;
    }
}

// ---------------- K2: parallel histogram build (64 blocks), atomic flush only ----------------
// No arrive counters, no spin gates — the kernel boundary is the sync. This is the
// round-1 histogram WITHOUT the 64us cross-block machinery, and takes the 102400
// LDS-atomic serial chain off the single CU that made round-4's k_topk 59us.
__global__ __launch_bounds__(1024) void k_hist(const float* __restrict__ scores,
                                               uint32_t* __restrict__ hist) {
    __shared__ uint32_t lh[NBINS];
    const int tid = threadIdx.x;
    for (int i = tid; i < NBINS; i += 1024) lh[i] = 0u;
    __syncthreads();
    int base = blockIdx.x * 1600;
    for (int k = tid; k < 1600; k += 1024) {
        uint32_t bin = __float_as_uint(scores[base + k]) >> 16;
        atomicAdd(&lh[bin], 1u);
    }
    __syncthreads();
    for (int i = tid; i < NBINS; i += 1024) {
        uint32_t c = lh[i];
        if (c) atomicAdd(&hist[i], c);
    }
}

// ---------------- K3: single-block cutoff -> collect -> bucket-rank -> decode ----------------
// rank(c) = suffix(bin_c + 1) + #{same-bin keys > key_c}. Fine histogram is prebuilt
// by k_hist; this block only loads it (64 KB), scans, collects, bucket-ranks, decodes.
__global__ __launch_bounds__(1024) void k_topk(const float* __restrict__ scores,
                                               const uint32_t* __restrict__ hist,
                                               const uint32_t* __restrict__ labels,
                                               const float* __restrict__ reg,
                                               float* __restrict__ out,
                                               float* __restrict__ boxes,
                                               uint32_t* __restrict__ lab1k) {
    __shared__ uint32_t lh[NBINS];        // 64 KB fine histogram (loaded from global)
    __shared__ uint32_t coarse[1025];     // suffix sums at 16-bin granularity
    __shared__ uint64_t skey[4096];       // candidate keys, bucketed by bin
    __shared__ uint32_t cnt[2048];        // per-bin arrival counters, indexed bin-cut
    __shared__ uint16_t sst[4096];        // bucket start per slot
    __shared__ uint16_t sen[4096];        // bucket end per slot
    __shared__ uint32_t s_cut, s_m;

    const int tid = threadIdx.x;
    for (int i = tid; i < NBINS; i += 1024) lh[i] = hist[i];
    for (int i = tid; i < 2048; i += 1024) cnt[i] = 0u;
    if (tid == 0) { s_cut = 0u; coarse[1024] = 0u; }
    __syncthreads();

    // --- coarse sums (16 bins/thread) + suffix scan; lh keeps original counts ---
    {
        uint32_t s = 0;
#pragma unroll
        for (int b = 0; b < 16; ++b) s += lh[tid * 16 + b];
        coarse[tid] = s;
    }
    __syncthreads();
    for (int off = 1; off < 1024; off <<= 1) {
        uint32_t v = coarse[tid] + ((tid + off < 1024) ? coarse[tid + off] : 0u);
        __syncthreads();
        coarse[tid] = v;
        __syncthreads();
    }
    {
        uint32_t inc   = coarse[tid];
        uint32_t above = (tid < 1023) ? coarse[tid + 1] : 0u;
        if (above < K_TOP && inc >= K_TOP) {
            uint32_t c2 = above;
            for (int b = 15; b >= 0; --b) {
                c2 += lh[tid * 16 + b];
                if (c2 >= K_TOP) { s_cut = (uint32_t)(tid * 16 + b); break; }
            }
        }
    }
    __syncthreads();
    const uint32_t cut = s_cut;
    if (tid == 0) {
        // M = suffix(cut)  (reads coarse/lh only; racers below also only read them)
        uint32_t tc = cut >> 4;
        uint32_t m = coarse[tc + 1];
        for (uint32_t k2 = cut; k2 < tc * 16 + 16; ++k2) m += lh[k2];
        s_m = (m > 4096u) ? 4096u : m;
    }

    // --- collect: bucketed append.  bucket(b) occupies [suffix(b+1), suffix(b)) ---
    const float4* s4 = (const float4*)scores;
    for (int k = tid; k < N_ANCH / 4; k += 1024) {
        float4 v = s4[k];
        uint32_t bb[4] = { __float_as_uint(v.x), __float_as_uint(v.y),
                           __float_as_uint(v.z), __float_as_uint(v.w) };
#pragma unroll
        for (int c = 0; c < 4; ++c) {
            uint32_t b = bb[c] >> 16;
            if (b >= cut) {
                uint32_t tb = b >> 4;
                uint32_t base = coarse[tb + 1];
                for (uint32_t k2 = b + 1; k2 < tb * 16 + 16; ++k2) base += lh[k2];
                uint32_t sp = b - cut;
                if (sp < 2048u) {   // span guard (keeps memory-safety for degenerate data)
                    uint32_t slot = atomicAdd(&cnt[sp], 1u);
                    uint32_t pos  = base + slot;
                    uint32_t end  = base + lh[b];
                    if (pos < 4096u) {
                        skey[pos] = ((uint64_t)bb[c] << 32) |
                                    (uint64_t)(0xFFFFFFFFu - (uint32_t)(k * 4 + c));
                        sst[pos] = (uint16_t)base;
                        sen[pos] = (uint16_t)((end > 4096u) ? 4096u : end);
                    }
                }
            }
        }
    }
    __syncthreads();

    // --- bucket-rank + decode epilogue ---
    const uint32_t M = s_m;
    for (uint32_t s2 = tid; s2 < M; s2 += 1024) {
        uint64_t key = skey[s2];
        uint32_t st = sst[s2], en = sen[s2];
        uint32_t r = st;
        for (uint32_t u = st; u < en; ++u) r += (skey[u] > key) ? 1u : 0u;
        if (r >= K_TOP) continue;
        int t = (int)r;
        uint32_t sbits = (uint32_t)(key >> 32);
        uint32_t idx   = 0xFFFFFFFFu - (uint32_t)(key & 0xFFFFFFFFull);
        float score = __uint_as_float(sbits);
        uint32_t lab = labels[idx];
        out[t]         = score;
        out[K_TOP + t] = (float)lab;
        lab1k[t]       = lab;
        float ax = (float)(idx % FMP);
        float ay = (float)(idx / FMP);
        float4 rr = ((const float4*)reg)[idx];
        float e0 = expf(fminf(rr.x, SC_CLAMP));
        float e1 = expf(fminf(rr.y, SC_CLAMP));
        float e2 = expf(fminf(rr.z, SC_CLAMP));
        float e3 = expf(fminf(rr.w, SC_CLAMP));
        float x1 = fminf(fmaxf((ax - e0) * 4.0f / IMGF, 0.0f), 1.0f);
        float y1 = fminf(fmaxf((ay - e1) * 4.0f / IMGF, 0.0f), 1.0f);
        float x2 = fminf(fmaxf((ax + e2) * 4.0f / IMGF, 0.0f), 1.0f);
        float y2 = fminf(fmaxf((ay + e3) * 4.0f / IMGF, 0.0f), 1.0f);
        out[2 * K_TOP + t * 4 + 0] = x1;
        out[2 * K_TOP + t * 4 + 1] = y1;
        out[2 * K_TOP + t * 4 + 2] = x2;
        out[2 * K_TOP + t * 4 + 3] = y2;
        boxes[t * 4 + 0] = x1;
        boxes[t * 4 + 1] = y1;
        boxes[t * 4 + 2] = x2;
        boxes[t * 4 + 3] = y2;
    }
}

// ---------------- K4: suppress masks, one wave per row (63 x 1024) ----------------
__global__ __launch_bounds__(1024) void k_mask(const float* __restrict__ boxes,
                                               const uint32_t* __restrict__ lab1k,
                                               uint64_t* __restrict__ mask,
                                               uint64_t* __restrict__ diag) {
    int r = blockIdx.x * 16 + (threadIdx.x >> 6);
    int lane = threadIdx.x & 63;
    if (r >= K_TOP) return;
    float4 bi = ((const float4*)boxes)[r];
    uint32_t li = lab1k[r];
    float areai = (bi.z - bi.x) * (bi.w - bi.y);
    int iw = r >> 6;
    uint64_t dw = 0ull;
#pragma unroll
    for (int w = 0; w < 16; ++w) {
        int j = w * 64 + lane;
        bool sup = false;
        if (j < K_TOP && j > r) {
            float4 bj = ((const float4*)boxes)[j];
            float areaj = (bj.z - bj.x) * (bj.w - bj.y);
            float xx1 = fmaxf(bi.x, bj.x);
            float yy1 = fmaxf(bi.y, bj.y);
            float xx2 = fminf(bi.z, bj.z);
            float yy2 = fminf(bi.w, bj.w);
            float ww = fmaxf(1e-10f, xx2 - xx1);
            float hh = fmaxf(1e-10f, yy2 - yy1);
            float inter = ww * hh;
            float iouv = inter / (areai + areaj - inter + 1e-10f);
            sup = (iouv > NMS_T) && (li == lab1k[j]);
        }
        unsigned long long m = __ballot(sup);
        if (lane == 0) mask[(size_t)r * 16 + w] = (uint64_t)m;
        if (w == iw) dw = (uint64_t)m;
    }
    if (lane == 0) diag[r] = dw;
}

// ---------------- K5: greedy scan, single wave, full register budget ----------------
// launch_bounds(64,1): VGPR cap ~512 so bun[16] (32 VGPRs) can't spill
// (earlier fused versions compiled at VGPR=40 -> scratch -> 70-100us).
__global__ __launch_bounds__(64, 1) void k_scan(const uint64_t* __restrict__ mask,
                                                const uint64_t* __restrict__ diag,
                                                float* __restrict__ out) {
    int lane = threadIdx.x;
    int q = lane >> 4, wrd = lane & 15;
    uint64_t remv = 0ull;
    uint64_t dcur = diag[lane];
    for (int g = 0; g < 16; ++g) {
        uint64_t dnxt = (g < 15) ? diag[64 * (g + 1) + lane] : 0ull;
        uint64_t bun[16];
        if (g < 15) {
#pragma unroll
            for (int r4 = 0; r4 < 16; ++r4)
                bun[r4] = mask[(size_t)(64 * g + 4 * r4 + q) * 16 + wrd];
        }
        uint32_t dlo = 0, dhi = 0;
#pragma unroll
        for (int qq = 0; qq < 4; ++qq) {
            dlo |= __builtin_amdgcn_readlane((uint32_t)remv, qq * 16 + g);
            dhi |= __builtin_amdgcn_readlane((uint32_t)(remv >> 32), qq * 16 + g);
        }
        uint64_t D = ((uint64_t)dhi << 32) | dlo;
#pragma unroll
        for (int b = 0; b < 64; ++b) {
            uint32_t tlo = __builtin_amdgcn_readlane((uint32_t)dcur, b);
            uint32_t thi = __builtin_amdgcn_readlane((uint32_t)(dcur >> 32), b);
            uint64_t T = ((uint64_t)thi << 32) | tlo;
            uint64_t sel = ((D >> b) & 1ull) - 1ull;   // ~0 if row kept
            D |= T & sel;
        }
        uint64_t keepg = ~D;
        int j = g * 64 + lane;
        if (j < K_TOP) out[6 * K_TOP + j] = (float)((keepg >> lane) & 1ull);
        if (g < 15) {
#pragma unroll
            for (int r4 = 0; r4 < 16; ++r4) {
                uint32_t kb = (uint32_t)(keepg >> (4 * r4 + q)) & 1u;
                uint64_t mm = 0ull - (uint64_t)kb;
                remv |= bun[r4] & mm;
            }
        }
        dcur = dnxt;
    }
}

extern "C" void kernel_launch(void* const* d_in, const int* in_sizes, int n_in,
                              void* d_out, int out_size, void* d_ws, size_t ws_size,
                              hipStream_t stream) {
    const float* hmp = (const float*)d_in[0];
    const float* reg = (const float*)d_in[1];
    const float* iou = (const float*)d_in[2];
    float* out = (float*)d_out;
    char* ws = (char*)d_ws;

    float*    scores = (float*)(ws + OFF_SCORES);
    uint32_t* labels = (uint32_t*)(ws + OFF_LABELS);
    uint32_t* hist   = (uint32_t*)(ws + OFF_HIST);
    float*    boxes  = (float*)(ws + OFF_BOXES);
    uint32_t* lab1k  = (uint32_t*)(ws + OFF_LAB1K);
    uint64_t* mask   = (uint64_t*)(ws + OFF_MASK);
    uint64_t* diag   = (uint64_t*)(ws + OFF_DIAG);

    k_scores<<<dim3(N_ANCH * 4 / 256), dim3(256), 0, stream>>>(hmp, iou, scores, labels, hist, diag);
    k_hist<<<dim3(64), dim3(1024), 0, stream>>>(scores, hist);
    k_topk<<<dim3(1), dim3(1024), 0, stream>>>(scores, hist, labels, reg, out, boxes, lab1k);
    k_mask<<<dim3(63), dim3(1024), 0, stream>>>(boxes, lab1k, mask, diag);
    k_scan<<<dim3(1), dim3(64), 0, stream>>>(mask, diag, out);
}

// Round 6
// 135.940 us; speedup vs baseline: 1.3110x; 1.3070x over previous
//
#include <hip/hip_runtime.h>
#include <stdint.h>

#define N_ANCH 102400
#define FMP 320
#define K_TOP 1000
#define NMS_T 0.6f
#define SC_CLAMP 6.907755278982137f
#define IMGF 1280.0f
#define NBINS 16384   // scores in (0,1) => float bits>>16 < 0x4000

// ---- workspace layout (bytes) ----
#define OFF_SCORES   0u          // f32[102400]
#define OFF_LABELS   409600u     // u32[102400]
#define OFF_HIST     819200u     // u32[16384]
#define OFF_META     884736u     // u32[64]: [2]=cand ctr
#define OFF_KEYS     884992u     // u64[4096]
#define OFF_BOXES    917760u     // f32[4000]
#define OFF_LAB1K    933760u     // u32[1000]
#define OFF_MASK     937760u     // u64[16000]
#define OFF_DIAG     1065760u    // u64[1024]

__device__ __forceinline__ float sigf(float x) {
    return 1.0f / (1.0f + expf(-x));
}

// ---------------- K1: scores+argmax; fused zeroing of hist/meta/diag ----------------
__global__ __launch_bounds__(256) void k_scores(const float* __restrict__ hmp,
                                                const float* __restrict__ iou,
                                                float* __restrict__ scores,
                                                uint32_t* __restrict__ labels,
                                                uint32_t* __restrict__ hist,
                                                uint32_t* __restrict__ meta,
                                                uint64_t* __restrict__ diag) {
    int blk = blockIdx.x;
    if (blk < 64) {
        hist[blk * 256 + threadIdx.x] = 0u;     // 64*256 = 16384 bins zeroed
    } else if (blk == 64) {
        if (threadIdx.x < 64) meta[threadIdx.x] = 0u;
        // zero diag (k_mask only rewrites rows < 1000; k_scan reads all 1024;
        // harness re-poisons ws every iteration so this is mandatory)
#pragma unroll
        for (int k = 0; k < 4; ++k) diag[threadIdx.x * 4 + k] = 0ull;
    }
    int gid = blk * 256 + threadIdx.x;
    int a = gid >> 2;
    int q = gid & 3;
    float si = sigf(iou[a]);
    const float4* row4 = (const float4*)hmp + (size_t)a * 20 + q;
    float4 v[5];
#pragma unroll
    for (int j = 0; j < 5; ++j) v[j] = row4[j * 4];
    float best = -1.0f;
    int bc = 0;
#pragma unroll
    for (int j = 0; j < 5; ++j) {
        int cb = j * 16 + q * 4;
        float f;
        f = sqrtf(sigf(v[j].x) * si); if (f > best) { best = f; bc = cb; }
        f = sqrtf(sigf(v[j].y) * si); if (f > best) { best = f; bc = cb + 1; }
        f = sqrtf(sigf(v[j].z) * si); if (f > best) { best = f; bc = cb + 2; }
        f = sqrtf(sigf(v[j].w) * si); if (f > best) { best = f; bc = cb + 3; }
    }
#pragma unroll
    for (int off = 1; off <= 2; off <<= 1) {
        float of = __shfl_xor(best, off);
        int   oc = __shfl_xor(bc, off);
        if (of > best || (of == best && oc < bc)) { best = of; bc = oc; }
    }
    if (q == 0) {
        scores[a] = best;
        labels[a] = (uint32_t)bc;
    }
}

// ---------------- K2: parallel histogram build (32 blocks), atomic flush only ----------------
// Kernel boundary is the sync. 32 blocks (vs 64) halves global-atomic flush contention.
__global__ __launch_bounds__(1024) void k_hist(const float* __restrict__ scores,
                                               uint32_t* __restrict__ hist) {
    __shared__ uint32_t lh[NBINS];
    const int tid = threadIdx.x;
    for (int i = tid; i < NBINS; i += 1024) lh[i] = 0u;
    __syncthreads();
    int base = blockIdx.x * 3200;
    for (int k = tid; k < 3200; k += 1024) {
        uint32_t bin = __float_as_uint(scores[base + k]) >> 16;
        atomicAdd(&lh[bin], 1u);
    }
    __syncthreads();
    for (int i = tid; i < NBINS; i += 1024) {
        uint32_t c = lh[i];
        if (c) atomicAdd(&hist[i], c);
    }
}

// ---------------- K3: 64 blocks; each redundantly computes cut, then collects its slice ----------------
// cut is a deterministic function of the complete hist, so all blocks agree without
// any cross-block exchange. Append is block-aggregated (one global atomic per block).
// This removes ALL serial single-CU work from the top-k phase except a 1024-wide scan
// that now runs in parallel copies.
__global__ __launch_bounds__(1024) void k_cutcollect(const float* __restrict__ scores,
                                                     const uint32_t* __restrict__ hist,
                                                     uint32_t* __restrict__ meta,
                                                     uint64_t* __restrict__ keys) {
    __shared__ uint32_t lh[NBINS];        // 64 KB fine histogram
    __shared__ uint32_t coarse[1024];     // suffix sums at 16-bin granularity
    __shared__ uint32_t s_cut, cnt, cbase;

    const int tid = threadIdx.x;
    for (int i = tid; i < NBINS; i += 1024) lh[i] = hist[i];
    if (tid == 0) { s_cut = 0u; cnt = 0u; }
    __syncthreads();

    // --- coarse sums (16 bins/thread) + suffix scan; lh keeps original counts ---
    {
        uint32_t s = 0;
#pragma unroll
        for (int b = 0; b < 16; ++b) s += lh[tid * 16 + b];
        coarse[tid] = s;
    }
    __syncthreads();
    for (int off = 1; off < 1024; off <<= 1) {
        uint32_t v = coarse[tid] + ((tid + off < 1024) ? coarse[tid + off] : 0u);
        __syncthreads();
        coarse[tid] = v;
        __syncthreads();
    }
    {
        uint32_t inc   = coarse[tid];
        uint32_t above = (tid < 1023) ? coarse[tid + 1] : 0u;
        if (above < K_TOP && inc >= K_TOP) {
            uint32_t c2 = above;
            for (int b = 15; b >= 0; --b) {
                c2 += lh[tid * 16 + b];
                if (c2 >= K_TOP) { s_cut = (uint32_t)(tid * 16 + b); break; }
            }
        }
    }
    __syncthreads();

    // --- collect this block's 1600 scores; block-aggregated append ---
    const uint32_t cut = s_cut;
    int base = blockIdx.x * 1600;
    uint32_t mybits[2], myi[2], mypos[2];
    int nc = 0;
    for (int k = tid; k < 1600; k += 1024) {
        int i = base + k;
        uint32_t bits = __float_as_uint(scores[i]);
        if ((bits >> 16) >= cut) {
            mypos[nc] = atomicAdd(&cnt, 1u);
            mybits[nc] = bits;
            myi[nc] = (uint32_t)i;
            ++nc;
        }
    }
    __syncthreads();
    if (tid == 0) cbase = cnt ? atomicAdd(&meta[2], cnt) : 0u;
    __syncthreads();
    for (int c = 0; c < nc; ++c) {
        uint32_t p = cbase + mypos[c];
        if (p < 4096u)
            keys[p] = ((uint64_t)mybits[c] << 32) | (uint64_t)(0xFFFFFFFFu - myi[c]);
    }
}

// ---------------- K4: rank (wave per candidate) + decode epilogue ----------------
__global__ __launch_bounds__(1024) void k_rank(const uint64_t* __restrict__ keys,
                                               const uint32_t* __restrict__ meta,
                                               const uint32_t* __restrict__ labels,
                                               const float* __restrict__ reg,
                                               float* __restrict__ out,
                                               float* __restrict__ boxes,
                                               uint32_t* __restrict__ lab1k) {
    __shared__ uint64_t sk[4096];
    uint32_t M = meta[2];
    if (M > 4096u) M = 4096u;
    if ((uint32_t)(blockIdx.x * 16) >= M) return;
    for (uint32_t i = threadIdx.x; i < M; i += 1024) sk[i] = keys[i];
    __syncthreads();
    int lane = threadIdx.x & 63;
    int wg = blockIdx.x * 16 + (threadIdx.x >> 6);
    if ((uint32_t)wg >= M) return;
    uint64_t mykey = sk[wg];
    uint32_t rank = 0;
    for (uint32_t j = lane; j < M; j += 64) rank += (sk[j] > mykey) ? 1u : 0u;
#pragma unroll
    for (int off = 32; off; off >>= 1) rank += __shfl_xor(rank, off);
    if (lane != 0 || rank >= K_TOP) return;
    int t = (int)rank;
    uint32_t sbits = (uint32_t)(mykey >> 32);
    uint32_t idx   = 0xFFFFFFFFu - (uint32_t)(mykey & 0xFFFFFFFFull);
    float score = __uint_as_float(sbits);
    uint32_t lab = labels[idx];
    out[t]         = score;
    out[K_TOP + t] = (float)lab;
    lab1k[t]       = lab;
    float ax = (float)(idx % FMP);
    float ay = (float)(idx / FMP);
    float4 rr = ((const float4*)reg)[idx];
    float e0 = expf(fminf(rr.x, SC_CLAMP));
    float e1 = expf(fminf(rr.y, SC_CLAMP));
    float e2 = expf(fminf(rr.z, SC_CLAMP));
    float e3 = expf(fminf(rr.w, SC_CLAMP));
    float x1 = fminf(fmaxf((ax - e0) * 4.0f / IMGF, 0.0f), 1.0f);
    float y1 = fminf(fmaxf((ay - e1) * 4.0f / IMGF, 0.0f), 1.0f);
    float x2 = fminf(fmaxf((ax + e2) * 4.0f / IMGF, 0.0f), 1.0f);
    float y2 = fminf(fmaxf((ay + e3) * 4.0f / IMGF, 0.0f), 1.0f);
    out[2 * K_TOP + t * 4 + 0] = x1;
    out[2 * K_TOP + t * 4 + 1] = y1;
    out[2 * K_TOP + t * 4 + 2] = x2;
    out[2 * K_TOP + t * 4 + 3] = y2;
    boxes[t * 4 + 0] = x1;
    boxes[t * 4 + 1] = y1;
    boxes[t * 4 + 2] = x2;
    boxes[t * 4 + 3] = y2;
}

// ---------------- K5: suppress masks, one wave per row (63 x 1024) ----------------
__global__ __launch_bounds__(1024) void k_mask(const float* __restrict__ boxes,
                                               const uint32_t* __restrict__ lab1k,
                                               uint64_t* __restrict__ mask,
                                               uint64_t* __restrict__ diag) {
    int r = blockIdx.x * 16 + (threadIdx.x >> 6);
    int lane = threadIdx.x & 63;
    if (r >= K_TOP) return;
    float4 bi = ((const float4*)boxes)[r];
    uint32_t li = lab1k[r];
    float areai = (bi.z - bi.x) * (bi.w - bi.y);
    int iw = r >> 6;
    uint64_t dw = 0ull;
#pragma unroll
    for (int w = 0; w < 16; ++w) {
        int j = w * 64 + lane;
        bool sup = false;
        if (j < K_TOP && j > r) {
            float4 bj = ((const float4*)boxes)[j];
            float areaj = (bj.z - bj.x) * (bj.w - bj.y);
            float xx1 = fmaxf(bi.x, bj.x);
            float yy1 = fmaxf(bi.y, bj.y);
            float xx2 = fminf(bi.z, bj.z);
            float yy2 = fminf(bi.w, bj.w);
            float ww = fmaxf(1e-10f, xx2 - xx1);
            float hh = fmaxf(1e-10f, yy2 - yy1);
            float inter = ww * hh;
            float iouv = inter / (areai + areaj - inter + 1e-10f);
            sup = (iouv > NMS_T) && (li == lab1k[j]);
        }
        unsigned long long m = __ballot(sup);
        if (lane == 0) mask[(size_t)r * 16 + w] = (uint64_t)m;
        if (w == iw) dw = (uint64_t)m;
    }
    if (lane == 0) diag[r] = dw;
}

// ---------------- K6: greedy scan, single wave, full register budget ----------------
// launch_bounds(64,1): VGPR cap ~512 so bun[16] (32 VGPRs) can't spill
// (earlier fused versions compiled at VGPR=40 -> scratch -> 70-100us).
__global__ __launch_bounds__(64, 1) void k_scan(const uint64_t* __restrict__ mask,
                                                const uint64_t* __restrict__ diag,
                                                float* __restrict__ out) {
    int lane = threadIdx.x;
    int q = lane >> 4, wrd = lane & 15;
    uint64_t remv = 0ull;
    uint64_t dcur = diag[lane];
    for (int g = 0; g < 16; ++g) {
        uint64_t dnxt = (g < 15) ? diag[64 * (g + 1) + lane] : 0ull;
        uint64_t bun[16];
        if (g < 15) {
#pragma unroll
            for (int r4 = 0; r4 < 16; ++r4)
                bun[r4] = mask[(size_t)(64 * g + 4 * r4 + q) * 16 + wrd];
        }
        uint32_t dlo = 0, dhi = 0;
#pragma unroll
        for (int qq = 0; qq < 4; ++qq) {
            dlo |= __builtin_amdgcn_readlane((uint32_t)remv, qq * 16 + g);
            dhi |= __builtin_amdgcn_readlane((uint32_t)(remv >> 32), qq * 16 + g);
        }
        uint64_t D = ((uint64_t)dhi << 32) | dlo;
#pragma unroll
        for (int b = 0; b < 64; ++b) {
            uint32_t tlo = __builtin_amdgcn_readlane((uint32_t)dcur, b);
            uint32_t thi = __builtin_amdgcn_readlane((uint32_t)(dcur >> 32), b);
            uint64_t T = ((uint64_t)thi << 32) | tlo;
            uint64_t sel = ((D >> b) & 1ull) - 1ull;   // ~0 if row kept
            D |= T & sel;
        }
        uint64_t keepg = ~D;
        int j = g * 64 + lane;
        if (j < K_TOP) out[6 * K_TOP + j] = (float)((keepg >> lane) & 1ull);
        if (g < 15) {
#pragma unroll
            for (int r4 = 0; r4 < 16; ++r4) {
                uint32_t kb = (uint32_t)(keepg >> (4 * r4 + q)) & 1u;
                uint64_t mm = 0ull - (uint64_t)kb;
                remv |= bun[r4] & mm;
            }
        }
        dcur = dnxt;
    }
}

extern "C" void kernel_launch(void* const* d_in, const int* in_sizes, int n_in,
                              void* d_out, int out_size, void* d_ws, size_t ws_size,
                              hipStream_t stream) {
    const float* hmp = (const float*)d_in[0];
    const float* reg = (const float*)d_in[1];
    const float* iou = (const float*)d_in[2];
    float* out = (float*)d_out;
    char* ws = (char*)d_ws;

    float*    scores = (float*)(ws + OFF_SCORES);
    uint32_t* labels = (uint32_t*)(ws + OFF_LABELS);
    uint32_t* hist   = (uint32_t*)(ws + OFF_HIST);
    uint32_t* meta   = (uint32_t*)(ws + OFF_META);
    uint64_t* keys   = (uint64_t*)(ws + OFF_KEYS);
    float*    boxes  = (float*)(ws + OFF_BOXES);
    uint32_t* lab1k  = (uint32_t*)(ws + OFF_LAB1K);
    uint64_t* mask   = (uint64_t*)(ws + OFF_MASK);
    uint64_t* diag   = (uint64_t*)(ws + OFF_DIAG);

    k_scores<<<dim3(N_ANCH * 4 / 256), dim3(256), 0, stream>>>(hmp, iou, scores, labels, hist, meta, diag);
    k_hist<<<dim3(32), dim3(1024), 0, stream>>>(scores, hist);
    k_cutcollect<<<dim3(64), dim3(1024), 0, stream>>>(scores, hist, meta, keys);
    k_rank<<<dim3(256), dim3(1024), 0, stream>>>(keys, meta, labels, reg, out, boxes, lab1k);
    k_mask<<<dim3(63), dim3(1024), 0, stream>>>(boxes, lab1k, mask, diag);
    k_scan<<<dim3(1), dim3(64), 0, stream>>>(mask, diag, out);
}